// Round 13
// baseline (282.159 us; speedup 1.0000x reference)
//
#include <hip/hip_runtime.h>
#include <stdint.h>

#define NEGF (-1e30f)

typedef unsigned short ushort_t;
typedef unsigned char uchar_t;
typedef __attribute__((ext_vector_type(2))) long v2i64;
typedef __attribute__((ext_vector_type(4))) float f32x4;

constexpr int cB = 4, cT = 256, cU = 64, cU1 = 65, cV = 1024, cF = 80, cH = 512, cJ = 512;
constexpr int cM = cB * cT * cU1; // 66560
constexpr int cTU = cT * cU1;     // 16640 (per-batch (u,t) plane: u*256+t)

// Padé(2,2) tanh + clamp: max err ~0.016, far below fp8-e4m3 half-step; no v_exp.
__device__ __forceinline__ float tanh_fast(float x){
  float t = x * x;
  float num = x * (27.f + t);
  float den = fmaf(9.f, t, 27.f);
  float r = num * __builtin_amdgcn_rcpf(den);
  return fminf(1.f, fmaxf(-1.f, r));
}

__device__ __forceinline__ float logadd(float x, float y){
  float m = fmaxf(x, y);
  return m + __logf(1.f + __expf(-fabsf(x - y)));
}

__device__ __forceinline__ int pk8(float a, float b, float c, float d){
  int v = __builtin_amdgcn_cvt_pk_fp8_f32(a, b, 0, false);
  v = __builtin_amdgcn_cvt_pk_fp8_f32(c, d, v, true);
  return v;
}

// wave-wide shift-up-by-1 on the VALU pipe (no ds_bpermute ~120cyc latency):
// row_shr:1 DPP + readlane/cndmask fixups for row-boundary lanes 16/32/48
// (writelane builtin is not exposed on this ROCm; readlane + ternary is).
// Lane 0 gets NEGF (DPP old operand, bound_ctrl=false).
__device__ __forceinline__ float shift_up1(float x, int lane){
  int xi = __float_as_int(x);
  int ri = __builtin_amdgcn_update_dpp(__float_as_int(NEGF), xi, 0x111, 0xF, 0xF, false);
  int s15 = __builtin_amdgcn_readlane(xi, 15);
  int s31 = __builtin_amdgcn_readlane(xi, 31);
  int s47 = __builtin_amdgcn_readlane(xi, 47);
  ri = (lane == 16) ? s15 : ri;
  ri = (lane == 32) ? s31 : ri;
  ri = (lane == 48) ? s47 : ri;
  return __int_as_float(ri);
}

// ------------- fused prologue: 3 independent jobs in one dispatch -------------
// bid 0..39   : Wcomb(80,512)  = W_enc @ W_jenc
// bid 40..169 : dmatb(260,512) = emb[padded] @ W_jdec + b_j
// bid 170..201: WTf8 fp8 fragment-order transpose of 32*W_out (2-ks-packed)
__global__ __launch_bounds__(256) void k_pre(
    const float* __restrict__ W_enc, const float* __restrict__ W_jenc,
    float* __restrict__ Wcomb,
    const float* __restrict__ emb, const int* __restrict__ targets,
    const float* __restrict__ W_jdec, const float* __restrict__ b_j,
    float* __restrict__ dmatb,
    const float* __restrict__ W_out, uchar_t* __restrict__ WTf8)
{
  __shared__ float sA[4][512];
  int bid = blockIdx.x;
  int tid = threadIdx.x;

  if (bid < 170){
    bool isW = (bid < 40);
    int id = isW ? bid : bid - 40;
    int bx = id & 1, by = id >> 1;
    int m0 = by * 4;
    int col = bx * 256 + tid;
    const float* Bm = isW ? W_jenc : W_jdec;
    for (int i = tid; i < 4 * 512; i += 256){
      int r = i >> 9, c = i & 511;
      if (isW){
        sA[r][c] = W_enc[(size_t)(m0 + r) * 512 + c];
      } else {
        int row = m0 + r;
        int b = row / cU1, u = row % cU1;
        int src = (u == 0) ? 0 : targets[b * cU + (u - 1)];
        sA[r][c] = emb[(size_t)src * cH + c];
      }
    }
    __syncthreads();
    float a0 = 0.f, a1 = 0.f, a2 = 0.f, a3 = 0.f;
#pragma unroll 8
    for (int k = 0; k < 512; k++){
      float bv = Bm[(size_t)k * cJ + col];
      a0 = fmaf(sA[0][k], bv, a0);
      a1 = fmaf(sA[1][k], bv, a1);
      a2 = fmaf(sA[2][k], bv, a2);
      a3 = fmaf(sA[3][k], bv, a3);
    }
    float bb = isW ? 0.f : b_j[col];
    float* C = isW ? Wcomb : dmatb;
    C[(size_t)(m0 + 0) * cJ + col] = a0 + bb;
    C[(size_t)(m0 + 1) * cJ + col] = a1 + bb;
    C[(size_t)(m0 + 2) * cJ + col] = a2 + bb;
    C[(size_t)(m0 + 3) * cJ + col] = a3 + bb;
  } else {
    // WTf8[((bn4*8+ksp)*16 + nt16)*1024 + lane*16]: 16 B = frag(ks=2ksp) || frag(ks=2ksp+1)
    int id = bid - 170;                  // 0..31
    int bn = id & 3, ksp = id >> 2;      // ksp 0..7
    int lane = tid & 63, nth = tid >> 6;
    int c16 = lane & 15, quad = lane >> 4;
    int jA = ksp * 64 + quad * 8;
#pragma unroll
    for (int i = 0; i < 4; i++){
      int nt16 = nth * 4 + i;
      int n = bn * 256 + nt16 * 16 + c16;
      unsigned int p[4];
#pragma unroll
      for (int h = 0; h < 4; h++){
        int j0 = jA + (h >> 1) * 32 + (h & 1) * 4;
        float w0 = W_out[(size_t)(j0 + 0) * cV + n] * 32.f;
        float w1 = W_out[(size_t)(j0 + 1) * cV + n] * 32.f;
        float w2 = W_out[(size_t)(j0 + 2) * cV + n] * 32.f;
        float w3 = W_out[(size_t)(j0 + 3) * cV + n] * 32.f;
        p[h] = (unsigned)pk8(w0, w1, w2, w3);
      }
      uint4 pack; pack.x = p[0]; pack.y = p[1]; pack.z = p[2]; pack.w = p[3];
      *(uint4*)(WTf8 + (((size_t)(bn * 8 + ksp) * 16 + nt16) * 64 + lane) * 16) = pack;
    }
  }
}

// ------------- e = inputs @ Wcomb  (K=80), 4 rows/block -------------
__global__ void k_gemm_e(const float* __restrict__ A, const float* __restrict__ Bm,
                         float* __restrict__ C){
  __shared__ float sA[4][80];
  int m0 = blockIdx.y * 4;
  int col = blockIdx.x * 256 + threadIdx.x;
  for (int i = threadIdx.x; i < 4 * 80; i += 256)
    sA[i / 80][i % 80] = A[(size_t)(m0 + i / 80) * 80 + (i % 80)];
  __syncthreads();
  float a0 = 0.f, a1 = 0.f, a2 = 0.f, a3 = 0.f;
#pragma unroll 8
  for (int k = 0; k < 80; k++){
    float bv = Bm[(size_t)k * cJ + col];
    a0 = fmaf(sA[0][k], bv, a0);
    a1 = fmaf(sA[1][k], bv, a1);
    a2 = fmaf(sA[2][k], bv, a2);
    a3 = fmaf(sA[3][k], bv, a3);
  }
  C[(size_t)(m0 + 0) * cJ + col] = a0;
  C[(size_t)(m0 + 1) * cJ + col] = a1;
  C[(size_t)(m0 + 2) * cJ + col] = a2;
  C[(size_t)(m0 + 3) * cJ + col] = a3;
}

// ------------- H fp8 fragment-order, t-minor, coalesced via LDS bounce -------------
__global__ __launch_bounds__(256) void k_hf(const float* __restrict__ e,
                                            const float* __restrict__ dmatb,
                                            uchar_t* __restrict__ Hbf8){
  __shared__ uchar_t sH[16 * 520];    // 16 rows x 512 B, pad 8 B
  int tid = threadIdx.x;
  int wid = tid >> 6, lane = tid & 63;
  int c16 = lane & 15, quad = lane >> 4;
  int bm = blockIdx.x;
  int bu = bm >> 1, thalf = bm & 1;
  int b = bu / cU1;
  int t0 = thalf * 128;

  float dj[8];
  const float4* dp = (const float4*)(dmatb + (size_t)bu * cJ + lane * 8);
  float4 dA = dp[0], dB = dp[1];
  dj[0] = dA.x; dj[1] = dA.y; dj[2] = dA.z; dj[3] = dA.w;
  dj[4] = dB.x; dj[5] = dB.y; dj[6] = dB.z; dj[7] = dB.w;

  const float* erow0 = e + ((size_t)(b * cT + t0)) * cJ + lane * 8;
  uchar_t* outb = Hbf8 + (size_t)bm * 65536 + lane * 16;

  for (int mg = 0; mg < 8; mg++){
#pragma unroll
    for (int rr = 0; rr < 4; rr++){
      int rloc = wid * 4 + rr;
      const float* ep = erow0 + ((size_t)(mg * 16 + rloc)) * cJ;
      float4 e0 = *(const float4*)ep;
      float4 e1 = *(const float4*)(ep + 4);
      int v0 = pk8(tanh_fast(e0.x + dj[0]), tanh_fast(e0.y + dj[1]),
                   tanh_fast(e0.z + dj[2]), tanh_fast(e0.w + dj[3]));
      int v1 = pk8(tanh_fast(e1.x + dj[4]), tanh_fast(e1.y + dj[5]),
                   tanh_fast(e1.z + dj[6]), tanh_fast(e1.w + dj[7]));
      uint2 pk; pk.x = (unsigned)v0; pk.y = (unsigned)v1;
      *(uint2*)(sH + rloc * 520 + lane * 8) = pk;
    }
    __syncthreads();
#pragma unroll
    for (int q = 0; q < 2; q++){
      int ksp = wid * 2 + q;
      uint2 lo = *(const uint2*)(sH + c16 * 520 + ksp * 64 + quad * 8);
      uint2 hi = *(const uint2*)(sH + c16 * 520 + ksp * 64 + 32 + quad * 8);
      uint4 pack; pack.x = lo.x; pack.y = lo.y; pack.z = hi.x; pack.w = hi.y;
      *(uint4*)(outb + ((size_t)ksp * 8 + mg) * 1024) = pack;
    }
    __syncthreads();
  }
}

// ------------- joint GEMM fp8: 64x64 wave tile, register-direct, 3 blocks/CU -------------
__global__ __launch_bounds__(256, 3) void k_joint(
    const uchar_t* __restrict__ Hbf8, const uchar_t* __restrict__ WTf8,
    const float* __restrict__ b_out, const int* __restrict__ targets,
    float* __restrict__ ps,                       // [8][cM]
    float* __restrict__ blank_g, float* __restrict__ lbl_g)
{
  __shared__ float redS[2][128];

  int tid = threadIdx.x;
  int wid = tid >> 6, lane = tid & 63;
  int quad = lane >> 4, c16 = lane & 15;
  int wm = wid & 1, wn = wid >> 1;
  int bid = blockIdx.x;
  int bm = ((bid >> 6) << 3) + (bid & 7);
  int bn = (bid >> 3) & 7;                       // 128-col strip
  int bu = bm >> 1, thalf = bm & 1;
  int b = bu / cU1, u = bu - b * cU1;
  int tg = (u < cU) ? targets[b * cU + u] : -1;
  int lin0 = bu * cT + thalf * 128;              // (b,u,t)-linear base

  f32x4 acc[4][4];
#pragma unroll
  for (int i = 0; i < 4; i++)
#pragma unroll
    for (int j = 0; j < 4; j++)
      acc[i][j] = (f32x4){0.f, 0.f, 0.f, 0.f};

  const uchar_t* aP = Hbf8 + (size_t)bm * 65536 + (wm * 4) * 1024 + lane * 16;
  const uchar_t* bP = WTf8 + (size_t)(bn >> 1) * 131072 + ((bn & 1) * 8 + wn * 4) * 1024 + lane * 16;

#pragma unroll
  for (int ksp = 0; ksp < 8; ksp++){
    v2i64 af[4], bf[4];
#pragma unroll
    for (int mt = 0; mt < 4; mt++)
      af[mt] = *(const v2i64*)(aP + (size_t)ksp * 8192 + mt * 1024);
#pragma unroll
    for (int nt = 0; nt < 4; nt++)
      bf[nt] = *(const v2i64*)(bP + (size_t)ksp * 16384 + nt * 1024);
#pragma unroll
    for (int h = 0; h < 2; h++)
#pragma unroll
      for (int mt = 0; mt < 4; mt++)
#pragma unroll
        for (int nt = 0; nt < 4; nt++)
          acc[mt][nt] = __builtin_amdgcn_mfma_f32_16x16x32_fp8_fp8(af[mt][h], bf[nt][h], acc[mt][nt], 0, 0, 0);
  }

  float bv[4];
#pragma unroll
  for (int nt = 0; nt < 4; nt++) bv[nt] = b_out[bn * 128 + (wn * 4 + nt) * 16 + c16];

  bool ownL = (tg >= 0) && ((tg >> 7) == bn) && (((tg >> 6) & 1) == wn);
  int ntO = (tg >> 4) & 3;
  int tgc = tg & 15;
  const float descale = 1.f / 32.f;     // undo the *32 on W_out fp8

#pragma unroll
  for (int mt = 0; mt < 4; mt++){
#pragma unroll
    for (int r = 0; r < 4; r++){
      int rl = wm * 64 + mt * 16 + quad * 4 + r;  // C/D: col=lane&15, row=quad*4+reg (m89)
      float l[4];
#pragma unroll
      for (int nt = 0; nt < 4; nt++) l[nt] = fmaf(acc[mt][nt][r], descale, bv[nt]);
      if (bn == 0 && wn == 0 && c16 == 0) blank_g[lin0 + rl] = l[0];
      if (ownL && c16 == tgc){
        float v = l[0];
#pragma unroll
        for (int k = 1; k < 4; k++) v = (ntO == k) ? l[k] : v;
        lbl_g[lin0 + rl] = v;
      }
      float s = __expf(l[0]) + __expf(l[1]) + __expf(l[2]) + __expf(l[3]);
      s += __shfl_xor(s, 1, 64);
      s += __shfl_xor(s, 2, 64);
      s += __shfl_xor(s, 4, 64);
      s += __shfl_xor(s, 8, 64);
      if (c16 == 0) redS[wn][rl] = s;
    }
  }
  __syncthreads();
  if (tid < 128)
    ps[(size_t)bn * cM + lin0 + tid] = redS[0][tid] + redS[1][tid];
}

// ------------- RNN-T alpha DP, (u,t) LDS layout, VALU-pipe shift -------------
// r11 counters: 550 cyc/step, VALUBusy 0.2% -> the chain was 2-3 ds_bpermute
// (~120 cyc each) per step. Fixes: (1) shfl_up -> row_shr:1 DPP + readlane
// fixups (VALU pipe); (2) u=64 track owned by lane 63 (zero cross-lane);
// (3) depth-2 scalar prefetch pipeline (named scalars only -- no arrays).
__global__ __launch_bounds__(256) void k_dp(
    const float* __restrict__ blank_g, const float* __restrict__ lbl_g,
    const float* __restrict__ ps,
    const int* __restrict__ in_len, const int* __restrict__ tgt_len,
    float* __restrict__ afin)
{
  __shared__ float sbb[cTU];   // 65 KB, (u,t): index u*256+t
  __shared__ float slb[cTU];   // 65 KB
  int b = blockIdx.x;
  size_t base = (size_t)b * cTU;
  for (int i = threadIdx.x; i < cTU; i += 256){
    size_t g = base + i;
    float S = 0.f;
#pragma unroll
    for (int p = 0; p < 8; p++) S += ps[(size_t)p * cM + g];
    float lse = __logf(S);
    sbb[i] = blank_g[g] - lse;
    slb[i] = ((i >> 8) < cU) ? (lbl_g[g] - lse) : NEGF;
  }
  __syncthreads();
  if (threadIdx.x >= 64) return;

  int u = threadIdx.x;                 // 0..63 (== lane)
  int til = in_len[b] - 1;
  int tl  = tgt_len[b];                // 32..64
  bool cap64 = (tl == 64);
  int ub = u << 8;
  int ubm1 = (u - 1) << 8;
  float fb   = sbb[(tl << 8) + til];   // blank lp at (u=tl, t=til)
  float fb64 = sbb[(64 << 8) + til];

  float Dprev = (u == 0) ? 0.f : NEGF; // D_d[u] = alpha[d-u][u]
  float D64prev = NEGF;                // lane 63 owns the u=64 track

  auto loadB = [&](int d) -> float {
    int tb = d - 1 - u;
    bool v = (tb >= 0) & (tb <= 255);
    float x = sbb[ub + (v ? tb : 0)];
    return v ? x : NEGF;
  };
  auto loadL = [&](int d) -> float {
    int t = d - u;
    bool v = (u >= 1) & (t >= 0) & (t <= 255) & ((u - 1) < tl);
    float x = slb[(v ? ubm1 : 0) + (v ? t : 0)];
    return v ? x : NEGF;
  };
  auto loadB64 = [&](int d) -> float {          // blank at (u=64, t=t64-1)
    int t64 = d - 64;
    bool v = (t64 >= 1) & (t64 <= 255);
    float x = sbb[(64 << 8) + (v ? (t64 - 1) : 0)];
    return v ? x : NEGF;
  };
  auto loadL64 = [&](int d) -> float {          // label at (u=63, t=t64)
    int t64 = d - 64;
    bool v = (t64 >= 0) & (t64 <= 255);
    float x = slb[(63 << 8) + (v ? t64 : 0)];
    return v ? x : NEGF;
  };

  auto step = [&](int d, float blv, float lvv, float b64v, float l63v){
    int t = d - u;
    bool tv = (t >= 0) & (t <= 255);
    float up = shift_up1(Dprev, u);
    float term1 = Dprev + blv;          // NEGF operands stay hugely negative; no NaN
    float term2 = up + lvv;
    float Dcur = tv ? logadd(term1, term2) : NEGF;
    if (u == tl && t == til) afin[b] = Dcur + fb;
    if (cap64){
      int t64 = d - 64;
      if (t64 >= 0 && t64 <= 255){
        float tA = D64prev + b64v;      // b64v = NEGF for t64 < 1
        float tB = Dprev + l63v;        // meaningful in lane 63 (alpha[t64][63])
        float D64 = logadd(tA, tB);
        if (t64 == til && u == 63) afin[b] = D64 + fb64;
        D64prev = D64;
      }
    }
    Dprev = Dcur;
  };

  // depth-2 pipeline, unroll-2, scalar slots A/B
  float bA = loadB(1), lA = loadL(1), pA = loadB64(1), qA = loadL64(1);
  float bB = loadB(2), lB = loadL(2), pB = loadB64(2), qB = loadL64(2);
  for (int d = 1; d <= 319; d += 2){
    float b0 = bA, l0 = lA, p0 = pA, q0 = qA;
    if (d + 2 <= 319){ bA = loadB(d + 2); lA = loadL(d + 2); pA = loadB64(d + 2); qA = loadL64(d + 2); }
    step(d, b0, l0, p0, q0);
    float b1 = bB, l1 = lB, p1 = pB, q1 = qB;
    if (d + 3 <= 319){ bB = loadB(d + 3); lB = loadL(d + 3); pB = loadB64(d + 3); qB = loadL64(d + 3); }
    if (d + 1 <= 319) step(d + 1, b1, l1, p1, q1);
  }
}

__global__ void k_final(const float* __restrict__ afin, float* __restrict__ out){
  if (threadIdx.x == 0)
    out[0] = -0.25f * (afin[0] + afin[1] + afin[2] + afin[3]);
}

extern "C" void kernel_launch(void* const* d_in, const int* in_sizes, int n_in,
                              void* d_out, int out_size, void* d_ws, size_t ws_size,
                              hipStream_t stream)
{
  (void)in_sizes; (void)n_in; (void)out_size; (void)ws_size;
  const float* inputs = (const float*)d_in[0];   // (4,256,80)
  const float* W_enc  = (const float*)d_in[1];   // (80,512)
  const float* emb    = (const float*)d_in[2];   // (1024,512)
  const float* W_jenc = (const float*)d_in[3];   // (512,512)
  const float* W_jdec = (const float*)d_in[4];   // (512,512)
  const float* b_j    = (const float*)d_in[5];   // (512)
  const float* W_out  = (const float*)d_in[6];   // (512,1024)
  const float* b_out  = (const float*)d_in[7];   // (1024)
  const int* targets  = (const int*)d_in[8];     // (4,64)
  const int* in_len   = (const int*)d_in[9];     // (4)
  const int* tgt_len  = (const int*)d_in[10];    // (4)

  char* w = (char*)d_ws;
  auto alloc = [&](size_t bytes){ char* p = w; w += (bytes + 255) & ~(size_t)255; return p; };
  float* Wcomb   = (float*)alloc((size_t)80 * 512 * 4);
  float* e       = (float*)alloc((size_t)1024 * 512 * 4);
  float* dmatb   = (float*)alloc((size_t)260 * 512 * 4);
  float* blank_g = (float*)alloc((size_t)cM * 4);
  float* lbl_g   = (float*)alloc((size_t)cM * 4);
  float* ps      = (float*)alloc((size_t)8 * cM * 4);
  float* afin    = (float*)alloc(256);
  uchar_t* Hbf8  = (uchar_t*)alloc((size_t)520 * 65536);
  uchar_t* WTf8  = (uchar_t*)alloc((size_t)4 * 131072);

  k_pre<<<202, 256, 0, stream>>>(W_enc, W_jenc, Wcomb, emb, targets, W_jdec, b_j, dmatb,
                                 W_out, WTf8);
  k_gemm_e<<<dim3(2, 256), 256, 0, stream>>>(inputs, Wcomb, e);
  k_hf<<<520, 256, 0, stream>>>(e, dmatb, Hbf8);
  k_joint<<<4160, 256, 0, stream>>>(Hbf8, WTf8, b_out, targets, ps, blank_g, lbl_g);
  k_dp<<<4, 256, 0, stream>>>(blank_g, lbl_g, ps, in_len, tgt_len, afin);
  k_final<<<1, 64, 0, stream>>>(afin, (float*)d_out);
}

// Round 14
// 257.787 us; speedup vs baseline: 1.0945x; 1.0945x over previous
//
#include <hip/hip_runtime.h>
#include <stdint.h>

#define NEGF (-1e30f)

typedef unsigned short ushort_t;
typedef unsigned char uchar_t;
typedef __attribute__((ext_vector_type(2))) long v2i64;
typedef __attribute__((ext_vector_type(4))) float f32x4;

constexpr int cB = 4, cT = 256, cU = 64, cU1 = 65, cV = 1024, cF = 80, cH = 512, cJ = 512;
constexpr int cM = cB * cT * cU1; // 66560
constexpr int cTU = cT * cU1;     // 16640 (per-batch (u,t) plane: u*256+t)

// Padé(2,2) tanh + clamp: max err ~0.016, far below fp8-e4m3 half-step; no v_exp.
__device__ __forceinline__ float tanh_fast(float x){
  float t = x * x;
  float num = x * (27.f + t);
  float den = fmaf(9.f, t, 27.f);
  float r = num * __builtin_amdgcn_rcpf(den);
  return fminf(1.f, fmaxf(-1.f, r));
}

__device__ __forceinline__ float logadd(float x, float y){
  float m = fmaxf(x, y);
  return m + __logf(1.f + __expf(-fabsf(x - y)));
}

__device__ __forceinline__ int pk8(float a, float b, float c, float d){
  int v = __builtin_amdgcn_cvt_pk_fp8_f32(a, b, 0, false);
  v = __builtin_amdgcn_cvt_pk_fp8_f32(c, d, v, true);
  return v;
}

// ------------- fused prologue: 3 independent jobs in one dispatch -------------
// bid 0..39   : Wcomb(80,512)  = W_enc @ W_jenc
// bid 40..169 : dmatb(260,512) = emb[padded] @ W_jdec + b_j
// bid 170..201: WTf8 fp8 fragment-order transpose of 32*W_out (2-ks-packed)
__global__ __launch_bounds__(256) void k_pre(
    const float* __restrict__ W_enc, const float* __restrict__ W_jenc,
    float* __restrict__ Wcomb,
    const float* __restrict__ emb, const int* __restrict__ targets,
    const float* __restrict__ W_jdec, const float* __restrict__ b_j,
    float* __restrict__ dmatb,
    const float* __restrict__ W_out, uchar_t* __restrict__ WTf8)
{
  __shared__ float sA[4][512];
  int bid = blockIdx.x;
  int tid = threadIdx.x;

  if (bid < 170){
    bool isW = (bid < 40);
    int id = isW ? bid : bid - 40;
    int bx = id & 1, by = id >> 1;
    int m0 = by * 4;
    int col = bx * 256 + tid;
    const float* Bm = isW ? W_jenc : W_jdec;
    for (int i = tid; i < 4 * 512; i += 256){
      int r = i >> 9, c = i & 511;
      if (isW){
        sA[r][c] = W_enc[(size_t)(m0 + r) * 512 + c];
      } else {
        int row = m0 + r;
        int b = row / cU1, u = row % cU1;
        int src = (u == 0) ? 0 : targets[b * cU + (u - 1)];
        sA[r][c] = emb[(size_t)src * cH + c];
      }
    }
    __syncthreads();
    float a0 = 0.f, a1 = 0.f, a2 = 0.f, a3 = 0.f;
#pragma unroll 8
    for (int k = 0; k < 512; k++){
      float bv = Bm[(size_t)k * cJ + col];
      a0 = fmaf(sA[0][k], bv, a0);
      a1 = fmaf(sA[1][k], bv, a1);
      a2 = fmaf(sA[2][k], bv, a2);
      a3 = fmaf(sA[3][k], bv, a3);
    }
    float bb = isW ? 0.f : b_j[col];
    float* C = isW ? Wcomb : dmatb;
    C[(size_t)(m0 + 0) * cJ + col] = a0 + bb;
    C[(size_t)(m0 + 1) * cJ + col] = a1 + bb;
    C[(size_t)(m0 + 2) * cJ + col] = a2 + bb;
    C[(size_t)(m0 + 3) * cJ + col] = a3 + bb;
  } else {
    // WTf8[((bn4*8+ksp)*16 + nt16)*1024 + lane*16]: 16 B = frag(ks=2ksp) || frag(ks=2ksp+1)
    int id = bid - 170;                  // 0..31
    int bn = id & 3, ksp = id >> 2;      // ksp 0..7
    int lane = tid & 63, nth = tid >> 6;
    int c16 = lane & 15, quad = lane >> 4;
    int jA = ksp * 64 + quad * 8;
#pragma unroll
    for (int i = 0; i < 4; i++){
      int nt16 = nth * 4 + i;
      int n = bn * 256 + nt16 * 16 + c16;
      unsigned int p[4];
#pragma unroll
      for (int h = 0; h < 4; h++){
        int j0 = jA + (h >> 1) * 32 + (h & 1) * 4;
        float w0 = W_out[(size_t)(j0 + 0) * cV + n] * 32.f;
        float w1 = W_out[(size_t)(j0 + 1) * cV + n] * 32.f;
        float w2 = W_out[(size_t)(j0 + 2) * cV + n] * 32.f;
        float w3 = W_out[(size_t)(j0 + 3) * cV + n] * 32.f;
        p[h] = (unsigned)pk8(w0, w1, w2, w3);
      }
      uint4 pack; pack.x = p[0]; pack.y = p[1]; pack.z = p[2]; pack.w = p[3];
      *(uint4*)(WTf8 + (((size_t)(bn * 8 + ksp) * 16 + nt16) * 64 + lane) * 16) = pack;
    }
  }
}

// ------------- e = inputs @ Wcomb  (K=80), 4 rows/block -------------
__global__ void k_gemm_e(const float* __restrict__ A, const float* __restrict__ Bm,
                         float* __restrict__ C){
  __shared__ float sA[4][80];
  int m0 = blockIdx.y * 4;
  int col = blockIdx.x * 256 + threadIdx.x;
  for (int i = threadIdx.x; i < 4 * 80; i += 256)
    sA[i / 80][i % 80] = A[(size_t)(m0 + i / 80) * 80 + (i % 80)];
  __syncthreads();
  float a0 = 0.f, a1 = 0.f, a2 = 0.f, a3 = 0.f;
#pragma unroll 8
  for (int k = 0; k < 80; k++){
    float bv = Bm[(size_t)k * cJ + col];
    a0 = fmaf(sA[0][k], bv, a0);
    a1 = fmaf(sA[1][k], bv, a1);
    a2 = fmaf(sA[2][k], bv, a2);
    a3 = fmaf(sA[3][k], bv, a3);
  }
  C[(size_t)(m0 + 0) * cJ + col] = a0;
  C[(size_t)(m0 + 1) * cJ + col] = a1;
  C[(size_t)(m0 + 2) * cJ + col] = a2;
  C[(size_t)(m0 + 3) * cJ + col] = a3;
}

// ------------- H fp8 fragment-order, t-minor, coalesced via LDS bounce -------------
__global__ __launch_bounds__(256) void k_hf(const float* __restrict__ e,
                                            const float* __restrict__ dmatb,
                                            uchar_t* __restrict__ Hbf8){
  __shared__ uchar_t sH[16 * 520];    // 16 rows x 512 B, pad 8 B
  int tid = threadIdx.x;
  int wid = tid >> 6, lane = tid & 63;
  int c16 = lane & 15, quad = lane >> 4;
  int bm = blockIdx.x;
  int bu = bm >> 1, thalf = bm & 1;
  int b = bu / cU1;
  int t0 = thalf * 128;

  float dj[8];
  const float4* dp = (const float4*)(dmatb + (size_t)bu * cJ + lane * 8);
  float4 dA = dp[0], dB = dp[1];
  dj[0] = dA.x; dj[1] = dA.y; dj[2] = dA.z; dj[3] = dA.w;
  dj[4] = dB.x; dj[5] = dB.y; dj[6] = dB.z; dj[7] = dB.w;

  const float* erow0 = e + ((size_t)(b * cT + t0)) * cJ + lane * 8;
  uchar_t* outb = Hbf8 + (size_t)bm * 65536 + lane * 16;

  for (int mg = 0; mg < 8; mg++){
#pragma unroll
    for (int rr = 0; rr < 4; rr++){
      int rloc = wid * 4 + rr;
      const float* ep = erow0 + ((size_t)(mg * 16 + rloc)) * cJ;
      float4 e0 = *(const float4*)ep;
      float4 e1 = *(const float4*)(ep + 4);
      int v0 = pk8(tanh_fast(e0.x + dj[0]), tanh_fast(e0.y + dj[1]),
                   tanh_fast(e0.z + dj[2]), tanh_fast(e0.w + dj[3]));
      int v1 = pk8(tanh_fast(e1.x + dj[4]), tanh_fast(e1.y + dj[5]),
                   tanh_fast(e1.z + dj[6]), tanh_fast(e1.w + dj[7]));
      uint2 pk; pk.x = (unsigned)v0; pk.y = (unsigned)v1;
      *(uint2*)(sH + rloc * 520 + lane * 8) = pk;
    }
    __syncthreads();
#pragma unroll
    for (int q = 0; q < 2; q++){
      int ksp = wid * 2 + q;
      uint2 lo = *(const uint2*)(sH + c16 * 520 + ksp * 64 + quad * 8);
      uint2 hi = *(const uint2*)(sH + c16 * 520 + ksp * 64 + 32 + quad * 8);
      uint4 pack; pack.x = lo.x; pack.y = lo.y; pack.z = hi.x; pack.w = hi.y;
      *(uint4*)(outb + ((size_t)ksp * 8 + mg) * 1024) = pack;
    }
    __syncthreads();
  }
}

// ------------- joint GEMM fp8: 64x64 wave tile, register-direct, 3 blocks/CU -------------
__global__ __launch_bounds__(256, 3) void k_joint(
    const uchar_t* __restrict__ Hbf8, const uchar_t* __restrict__ WTf8,
    const float* __restrict__ b_out, const int* __restrict__ targets,
    float* __restrict__ ps,                       // [8][cM]
    float* __restrict__ blank_g, float* __restrict__ lbl_g)
{
  __shared__ float redS[2][128];

  int tid = threadIdx.x;
  int wid = tid >> 6, lane = tid & 63;
  int quad = lane >> 4, c16 = lane & 15;
  int wm = wid & 1, wn = wid >> 1;
  int bid = blockIdx.x;
  int bm = ((bid >> 6) << 3) + (bid & 7);
  int bn = (bid >> 3) & 7;                       // 128-col strip
  int bu = bm >> 1, thalf = bm & 1;
  int b = bu / cU1, u = bu - b * cU1;
  int tg = (u < cU) ? targets[b * cU + u] : -1;
  int lin0 = bu * cT + thalf * 128;              // (b,u,t)-linear base

  f32x4 acc[4][4];
#pragma unroll
  for (int i = 0; i < 4; i++)
#pragma unroll
    for (int j = 0; j < 4; j++)
      acc[i][j] = (f32x4){0.f, 0.f, 0.f, 0.f};

  const uchar_t* aP = Hbf8 + (size_t)bm * 65536 + (wm * 4) * 1024 + lane * 16;
  const uchar_t* bP = WTf8 + (size_t)(bn >> 1) * 131072 + ((bn & 1) * 8 + wn * 4) * 1024 + lane * 16;

#pragma unroll
  for (int ksp = 0; ksp < 8; ksp++){
    v2i64 af[4], bf[4];
#pragma unroll
    for (int mt = 0; mt < 4; mt++)
      af[mt] = *(const v2i64*)(aP + (size_t)ksp * 8192 + mt * 1024);
#pragma unroll
    for (int nt = 0; nt < 4; nt++)
      bf[nt] = *(const v2i64*)(bP + (size_t)ksp * 16384 + nt * 1024);
#pragma unroll
    for (int h = 0; h < 2; h++)
#pragma unroll
      for (int mt = 0; mt < 4; mt++)
#pragma unroll
        for (int nt = 0; nt < 4; nt++)
          acc[mt][nt] = __builtin_amdgcn_mfma_f32_16x16x32_fp8_fp8(af[mt][h], bf[nt][h], acc[mt][nt], 0, 0, 0);
  }

  float bv[4];
#pragma unroll
  for (int nt = 0; nt < 4; nt++) bv[nt] = b_out[bn * 128 + (wn * 4 + nt) * 16 + c16];

  bool ownL = (tg >= 0) && ((tg >> 7) == bn) && (((tg >> 6) & 1) == wn);
  int ntO = (tg >> 4) & 3;
  int tgc = tg & 15;
  const float descale = 1.f / 32.f;     // undo the *32 on W_out fp8

#pragma unroll
  for (int mt = 0; mt < 4; mt++){
#pragma unroll
    for (int r = 0; r < 4; r++){
      int rl = wm * 64 + mt * 16 + quad * 4 + r;  // C/D: col=lane&15, row=quad*4+reg (m89)
      float l[4];
#pragma unroll
      for (int nt = 0; nt < 4; nt++) l[nt] = fmaf(acc[mt][nt][r], descale, bv[nt]);
      if (bn == 0 && wn == 0 && c16 == 0) blank_g[lin0 + rl] = l[0];
      if (ownL && c16 == tgc){
        float v = l[0];
#pragma unroll
        for (int k = 1; k < 4; k++) v = (ntO == k) ? l[k] : v;
        lbl_g[lin0 + rl] = v;
      }
      float s = __expf(l[0]) + __expf(l[1]) + __expf(l[2]) + __expf(l[3]);
      s += __shfl_xor(s, 1, 64);
      s += __shfl_xor(s, 2, 64);
      s += __shfl_xor(s, 4, 64);
      s += __shfl_xor(s, 8, 64);
      if (c16 == 0) redS[wn][rl] = s;
    }
  }
  __syncthreads();
  if (tid < 128)
    ps[(size_t)bn * cM + lin0 + tid] = redS[0][tid] + redS[1][tid];
}

// ------------- parallel lse merge: 8 ps planes -> blankd/lbld (same layout) -------------
// Runs on 260 blocks (whole machine) instead of inside k_dp's 4 blocks.
__global__ __launch_bounds__(256) void k_lse(
    const float* __restrict__ ps, const float* __restrict__ blank_g,
    const float* __restrict__ lbl_g,
    float* __restrict__ blankd, float* __restrict__ lbld)
{
  int cell = blockIdx.x * 256 + threadIdx.x;   // 66560 = 260*256
  float S = 0.f;
#pragma unroll
  for (int p = 0; p < 8; p++) S += ps[(size_t)p * cM + cell];
  float lse = __logf(S);
  int u = (cell % cTU) >> 8;
  blankd[cell] = blank_g[cell] - lse;
  lbld[cell] = (u < cU) ? (lbl_g[cell] - lse) : NEGF;
}

// ------------- RNN-T alpha DP, (u,t) LDS layout, r11-proven shuffle step -------------
// r13 post-mortem: DPP+readlane shift was SLOWER than ds_bpermute (+195 cyc/step,
// readlane hazards on the chain) -> reverted to __shfl. The ~17K bank-conflict count
// is the benign mandatory 2-way alias (64 lanes / 32 banks), not a real cost.
// This round: staging is 2 coalesced streams (lse pre-merged in k_lse), broadcast
// operands prefetched as scalars, finish values captured in registers (no in-loop
// global stores).
__global__ __launch_bounds__(256) void k_dp(
    const float* __restrict__ blankd, const float* __restrict__ lbld,
    const int* __restrict__ in_len, const int* __restrict__ tgt_len,
    float* __restrict__ afin)
{
  __shared__ float sbb[cTU];   // 65 KB, (u,t): index u*256+t
  __shared__ float slb[cTU];   // 65 KB
  int b = blockIdx.x;
  size_t base = (size_t)b * cTU;
  for (int i = threadIdx.x; i < cTU / 4; i += 256){
    ((float4*)sbb)[i] = ((const float4*)(blankd + base))[i];
    ((float4*)slb)[i] = ((const float4*)(lbld + base))[i];
  }
  __syncthreads();
  if (threadIdx.x >= 64) return;

  int u = threadIdx.x;                 // 0..63
  int til = in_len[b] - 1;
  int tl  = tgt_len[b];                // 32..64
  bool cap64 = (tl == 64);
  int ub = u << 8;
  int ubm1 = (u - 1) << 8;
  float fb   = sbb[(tl << 8) + til];   // blank lp at (u=tl, t=til)
  float fb64 = sbb[(64 << 8) + til];

  float Dprev = (u == 0) ? 0.f : NEGF; // D_d[u] = alpha[d-u][u]
  float D64prev = NEGF;
  float res = 0.f;                     // exactly one lane/one step captures the finish

  auto loadB = [&](int d) -> float {
    int tb = d - 1 - u;
    bool v = (tb >= 0) & (tb <= 255);
    float x = sbb[ub + (v ? tb : 0)];
    return v ? x : NEGF;
  };
  auto loadL = [&](int d) -> float {
    int t = d - u;
    bool v = (u >= 1) & (t >= 0) & (t <= 255) & ((u - 1) < tl);
    float x = slb[(v ? ubm1 : 0) + (v ? t : 0)];
    return v ? x : NEGF;
  };
  auto loadB64 = [&](int d) -> float {          // blank at (u=64, t=t64-1), broadcast
    int t64 = d - 64;
    bool v = (t64 >= 1) & (t64 <= 255);
    float x = sbb[(64 << 8) + (v ? (t64 - 1) : 0)];
    return v ? x : NEGF;
  };
  auto loadL64 = [&](int d) -> float {          // label at (u=63, t=t64), broadcast
    int t64 = d - 64;
    bool v = (t64 >= 0) & (t64 <= 255);
    float x = slb[(63 << 8) + (v ? t64 : 0)];
    return v ? x : NEGF;
  };

  float blv = loadB(1), lvv = loadL(1);
  float b64 = loadB64(1), l63 = loadL64(1);
  for (int d = 1; d <= 319; d++){
    float blv_c = blv, lvv_c = lvv, b64_c = b64, l63_c = l63;
    blv = loadB(d + 1); lvv = loadL(d + 1);
    b64 = loadB64(d + 1); l63 = loadL64(d + 1);
    int t = d - u;
    bool tv = (t >= 0) & (t <= 255);
    float up = __shfl_up(Dprev, 1, 64);
    float term1 = Dprev + blv_c;
    float term2 = up + lvv_c;
    float Dcur = tv ? logadd(term1, term2) : NEGF;
    if (u == tl && t == til) res = Dcur + fb;
    if (cap64){
      int t64 = d - 64;
      if (t64 >= 0 && t64 <= 255){
        float s63 = __shfl(Dprev, 63, 64);
        float tA = (t64 >= 1) ? (D64prev + b64_c) : NEGF;
        float tB = s63 + l63_c;
        float D64 = logadd(tA, tB);
        if (t64 == til && u == 0) res = D64 + fb64;
        D64prev = D64;
      }
    }
    Dprev = Dcur;
  }

  // butterfly-sum broadcasts the single captured value (others hold 0)
  res += __shfl_xor(res, 1, 64);
  res += __shfl_xor(res, 2, 64);
  res += __shfl_xor(res, 4, 64);
  res += __shfl_xor(res, 8, 64);
  res += __shfl_xor(res, 16, 64);
  res += __shfl_xor(res, 32, 64);
  if (u == 0) afin[b] = res;
}

__global__ void k_final(const float* __restrict__ afin, float* __restrict__ out){
  if (threadIdx.x == 0)
    out[0] = -0.25f * (afin[0] + afin[1] + afin[2] + afin[3]);
}

extern "C" void kernel_launch(void* const* d_in, const int* in_sizes, int n_in,
                              void* d_out, int out_size, void* d_ws, size_t ws_size,
                              hipStream_t stream)
{
  (void)in_sizes; (void)n_in; (void)out_size; (void)ws_size;
  const float* inputs = (const float*)d_in[0];   // (4,256,80)
  const float* W_enc  = (const float*)d_in[1];   // (80,512)
  const float* emb    = (const float*)d_in[2];   // (1024,512)
  const float* W_jenc = (const float*)d_in[3];   // (512,512)
  const float* W_jdec = (const float*)d_in[4];   // (512,512)
  const float* b_j    = (const float*)d_in[5];   // (512)
  const float* W_out  = (const float*)d_in[6];   // (512,1024)
  const float* b_out  = (const float*)d_in[7];   // (1024)
  const int* targets  = (const int*)d_in[8];     // (4,64)
  const int* in_len   = (const int*)d_in[9];     // (4)
  const int* tgt_len  = (const int*)d_in[10];    // (4)

  char* w = (char*)d_ws;
  auto alloc = [&](size_t bytes){ char* p = w; w += (bytes + 255) & ~(size_t)255; return p; };
  float* Wcomb   = (float*)alloc((size_t)80 * 512 * 4);
  float* e       = (float*)alloc((size_t)1024 * 512 * 4);
  float* dmatb   = (float*)alloc((size_t)260 * 512 * 4);
  float* blank_g = (float*)alloc((size_t)cM * 4);
  float* lbl_g   = (float*)alloc((size_t)cM * 4);
  float* ps      = (float*)alloc((size_t)8 * cM * 4);
  float* blankd  = (float*)alloc((size_t)cM * 4);
  float* lbld    = (float*)alloc((size_t)cM * 4);
  float* afin    = (float*)alloc(256);
  uchar_t* Hbf8  = (uchar_t*)alloc((size_t)520 * 65536);
  uchar_t* WTf8  = (uchar_t*)alloc((size_t)4 * 131072);

  k_pre<<<202, 256, 0, stream>>>(W_enc, W_jenc, Wcomb, emb, targets, W_jdec, b_j, dmatb,
                                 W_out, WTf8);
  k_gemm_e<<<dim3(2, 256), 256, 0, stream>>>(inputs, Wcomb, e);
  k_hf<<<520, 256, 0, stream>>>(e, dmatb, Hbf8);
  k_joint<<<4160, 256, 0, stream>>>(Hbf8, WTf8, b_out, targets, ps, blank_g, lbl_g);
  k_lse<<<260, 256, 0, stream>>>(ps, blank_g, lbl_g, blankd, lbld);
  k_dp<<<4, 256, 0, stream>>>(blankd, lbld, in_len, tgt_len, afin);
  k_final<<<1, 64, 0, stream>>>(afin, (float*)d_out);
}

// Round 15
// 244.176 us; speedup vs baseline: 1.1556x; 1.0557x over previous
//
#include <hip/hip_runtime.h>
#include <stdint.h>

#define NEGF (-1e30f)

typedef unsigned short ushort_t;
typedef unsigned char uchar_t;
typedef __attribute__((ext_vector_type(2))) long v2i64;
typedef __attribute__((ext_vector_type(4))) float f32x4;

constexpr int cB = 4, cT = 256, cU = 64, cU1 = 65, cV = 1024, cF = 80, cH = 512, cJ = 512;
constexpr int cM = cB * cT * cU1; // 66560
constexpr int cTU = cT * cU1;     // 16640 (per-batch (u,t) plane: u*256+t)

// Padé(2,2) tanh + clamp: max err ~0.016, far below fp8-e4m3 half-step; no v_exp.
__device__ __forceinline__ float tanh_fast(float x){
  float t = x * x;
  float num = x * (27.f + t);
  float den = fmaf(9.f, t, 27.f);
  float r = num * __builtin_amdgcn_rcpf(den);
  return fminf(1.f, fmaxf(-1.f, r));
}

__device__ __forceinline__ float logadd(float x, float y){
  float m = fmaxf(x, y);
  return m + __logf(1.f + __expf(-fabsf(x - y)));
}

__device__ __forceinline__ int pk8(float a, float b, float c, float d){
  int v = __builtin_amdgcn_cvt_pk_fp8_f32(a, b, 0, false);
  v = __builtin_amdgcn_cvt_pk_fp8_f32(c, d, v, true);
  return v;
}

// ------------- fused prologue: 3 independent jobs in one dispatch -------------
__global__ __launch_bounds__(256) void k_pre(
    const float* __restrict__ W_enc, const float* __restrict__ W_jenc,
    float* __restrict__ Wcomb,
    const float* __restrict__ emb, const int* __restrict__ targets,
    const float* __restrict__ W_jdec, const float* __restrict__ b_j,
    float* __restrict__ dmatb,
    const float* __restrict__ W_out, uchar_t* __restrict__ WTf8)
{
  __shared__ float sA[4][512];
  int bid = blockIdx.x;
  int tid = threadIdx.x;

  if (bid < 170){
    bool isW = (bid < 40);
    int id = isW ? bid : bid - 40;
    int bx = id & 1, by = id >> 1;
    int m0 = by * 4;
    int col = bx * 256 + tid;
    const float* Bm = isW ? W_jenc : W_jdec;
    for (int i = tid; i < 4 * 512; i += 256){
      int r = i >> 9, c = i & 511;
      if (isW){
        sA[r][c] = W_enc[(size_t)(m0 + r) * 512 + c];
      } else {
        int row = m0 + r;
        int b = row / cU1, u = row % cU1;
        int src = (u == 0) ? 0 : targets[b * cU + (u - 1)];
        sA[r][c] = emb[(size_t)src * cH + c];
      }
    }
    __syncthreads();
    float a0 = 0.f, a1 = 0.f, a2 = 0.f, a3 = 0.f;
#pragma unroll 8
    for (int k = 0; k < 512; k++){
      float bv = Bm[(size_t)k * cJ + col];
      a0 = fmaf(sA[0][k], bv, a0);
      a1 = fmaf(sA[1][k], bv, a1);
      a2 = fmaf(sA[2][k], bv, a2);
      a3 = fmaf(sA[3][k], bv, a3);
    }
    float bb = isW ? 0.f : b_j[col];
    float* C = isW ? Wcomb : dmatb;
    C[(size_t)(m0 + 0) * cJ + col] = a0 + bb;
    C[(size_t)(m0 + 1) * cJ + col] = a1 + bb;
    C[(size_t)(m0 + 2) * cJ + col] = a2 + bb;
    C[(size_t)(m0 + 3) * cJ + col] = a3 + bb;
  } else {
    int id = bid - 170;                  // 0..31
    int bn = id & 3, ksp = id >> 2;      // ksp 0..7
    int lane = tid & 63, nth = tid >> 6;
    int c16 = lane & 15, quad = lane >> 4;
    int jA = ksp * 64 + quad * 8;
#pragma unroll
    for (int i = 0; i < 4; i++){
      int nt16 = nth * 4 + i;
      int n = bn * 256 + nt16 * 16 + c16;
      unsigned int p[4];
#pragma unroll
      for (int h = 0; h < 4; h++){
        int j0 = jA + (h >> 1) * 32 + (h & 1) * 4;
        float w0 = W_out[(size_t)(j0 + 0) * cV + n] * 32.f;
        float w1 = W_out[(size_t)(j0 + 1) * cV + n] * 32.f;
        float w2 = W_out[(size_t)(j0 + 2) * cV + n] * 32.f;
        float w3 = W_out[(size_t)(j0 + 3) * cV + n] * 32.f;
        p[h] = (unsigned)pk8(w0, w1, w2, w3);
      }
      uint4 pack; pack.x = p[0]; pack.y = p[1]; pack.z = p[2]; pack.w = p[3];
      *(uint4*)(WTf8 + (((size_t)(bn * 8 + ksp) * 16 + nt16) * 64 + lane) * 16) = pack;
    }
  }
}

// ------------- e = inputs @ Wcomb  (K=80), 4 rows/block -------------
__global__ void k_gemm_e(const float* __restrict__ A, const float* __restrict__ Bm,
                         float* __restrict__ C){
  __shared__ float sA[4][80];
  int m0 = blockIdx.y * 4;
  int col = blockIdx.x * 256 + threadIdx.x;
  for (int i = threadIdx.x; i < 4 * 80; i += 256)
    sA[i / 80][i % 80] = A[(size_t)(m0 + i / 80) * 80 + (i % 80)];
  __syncthreads();
  float a0 = 0.f, a1 = 0.f, a2 = 0.f, a3 = 0.f;
#pragma unroll 8
  for (int k = 0; k < 80; k++){
    float bv = Bm[(size_t)k * cJ + col];
    a0 = fmaf(sA[0][k], bv, a0);
    a1 = fmaf(sA[1][k], bv, a1);
    a2 = fmaf(sA[2][k], bv, a2);
    a3 = fmaf(sA[3][k], bv, a3);
  }
  C[(size_t)(m0 + 0) * cJ + col] = a0;
  C[(size_t)(m0 + 1) * cJ + col] = a1;
  C[(size_t)(m0 + 2) * cJ + col] = a2;
  C[(size_t)(m0 + 3) * cJ + col] = a3;
}

// ------------- H fp8 fragment-order, t-minor, coalesced via LDS bounce -------------
__global__ __launch_bounds__(256) void k_hf(const float* __restrict__ e,
                                            const float* __restrict__ dmatb,
                                            uchar_t* __restrict__ Hbf8){
  __shared__ uchar_t sH[16 * 520];    // 16 rows x 512 B, pad 8 B
  int tid = threadIdx.x;
  int wid = tid >> 6, lane = tid & 63;
  int c16 = lane & 15, quad = lane >> 4;
  int bm = blockIdx.x;
  int bu = bm >> 1, thalf = bm & 1;
  int b = bu / cU1;
  int t0 = thalf * 128;

  float dj[8];
  const float4* dp = (const float4*)(dmatb + (size_t)bu * cJ + lane * 8);
  float4 dA = dp[0], dB = dp[1];
  dj[0] = dA.x; dj[1] = dA.y; dj[2] = dA.z; dj[3] = dA.w;
  dj[4] = dB.x; dj[5] = dB.y; dj[6] = dB.z; dj[7] = dB.w;

  const float* erow0 = e + ((size_t)(b * cT + t0)) * cJ + lane * 8;
  uchar_t* outb = Hbf8 + (size_t)bm * 65536 + lane * 16;

  for (int mg = 0; mg < 8; mg++){
#pragma unroll
    for (int rr = 0; rr < 4; rr++){
      int rloc = wid * 4 + rr;
      const float* ep = erow0 + ((size_t)(mg * 16 + rloc)) * cJ;
      float4 e0 = *(const float4*)ep;
      float4 e1 = *(const float4*)(ep + 4);
      int v0 = pk8(tanh_fast(e0.x + dj[0]), tanh_fast(e0.y + dj[1]),
                   tanh_fast(e0.z + dj[2]), tanh_fast(e0.w + dj[3]));
      int v1 = pk8(tanh_fast(e1.x + dj[4]), tanh_fast(e1.y + dj[5]),
                   tanh_fast(e1.z + dj[6]), tanh_fast(e1.w + dj[7]));
      uint2 pk; pk.x = (unsigned)v0; pk.y = (unsigned)v1;
      *(uint2*)(sH + rloc * 520 + lane * 8) = pk;
    }
    __syncthreads();
#pragma unroll
    for (int q = 0; q < 2; q++){
      int ksp = wid * 2 + q;
      uint2 lo = *(const uint2*)(sH + c16 * 520 + ksp * 64 + quad * 8);
      uint2 hi = *(const uint2*)(sH + c16 * 520 + ksp * 64 + 32 + quad * 8);
      uint4 pack; pack.x = lo.x; pack.y = lo.y; pack.z = hi.x; pack.w = hi.y;
      *(uint4*)(outb + ((size_t)ksp * 8 + mg) * 1024) = pack;
    }
    __syncthreads();
  }
}

// ------------- joint GEMM fp8: 64x64 wave tile, register-direct, 3 blocks/CU -------------
__global__ __launch_bounds__(256, 3) void k_joint(
    const uchar_t* __restrict__ Hbf8, const uchar_t* __restrict__ WTf8,
    const float* __restrict__ b_out, const int* __restrict__ targets,
    float* __restrict__ ps,                       // [8][cM]
    float* __restrict__ blank_g, float* __restrict__ lbl_g)
{
  __shared__ float redS[2][128];

  int tid = threadIdx.x;
  int wid = tid >> 6, lane = tid & 63;
  int quad = lane >> 4, c16 = lane & 15;
  int wm = wid & 1, wn = wid >> 1;
  int bid = blockIdx.x;
  int bm = ((bid >> 6) << 3) + (bid & 7);
  int bn = (bid >> 3) & 7;                       // 128-col strip
  int bu = bm >> 1, thalf = bm & 1;
  int b = bu / cU1, u = bu - b * cU1;
  int tg = (u < cU) ? targets[b * cU + u] : -1;
  int lin0 = bu * cT + thalf * 128;              // (b,u,t)-linear base

  f32x4 acc[4][4];
#pragma unroll
  for (int i = 0; i < 4; i++)
#pragma unroll
    for (int j = 0; j < 4; j++)
      acc[i][j] = (f32x4){0.f, 0.f, 0.f, 0.f};

  const uchar_t* aP = Hbf8 + (size_t)bm * 65536 + (wm * 4) * 1024 + lane * 16;
  const uchar_t* bP = WTf8 + (size_t)(bn >> 1) * 131072 + ((bn & 1) * 8 + wn * 4) * 1024 + lane * 16;

#pragma unroll
  for (int ksp = 0; ksp < 8; ksp++){
    v2i64 af[4], bf[4];
#pragma unroll
    for (int mt = 0; mt < 4; mt++)
      af[mt] = *(const v2i64*)(aP + (size_t)ksp * 8192 + mt * 1024);
#pragma unroll
    for (int nt = 0; nt < 4; nt++)
      bf[nt] = *(const v2i64*)(bP + (size_t)ksp * 16384 + nt * 1024);
#pragma unroll
    for (int h = 0; h < 2; h++)
#pragma unroll
      for (int mt = 0; mt < 4; mt++)
#pragma unroll
        for (int nt = 0; nt < 4; nt++)
          acc[mt][nt] = __builtin_amdgcn_mfma_f32_16x16x32_fp8_fp8(af[mt][h], bf[nt][h], acc[mt][nt], 0, 0, 0);
  }

  float bv[4];
#pragma unroll
  for (int nt = 0; nt < 4; nt++) bv[nt] = b_out[bn * 128 + (wn * 4 + nt) * 16 + c16];

  bool ownL = (tg >= 0) && ((tg >> 7) == bn) && (((tg >> 6) & 1) == wn);
  int ntO = (tg >> 4) & 3;
  int tgc = tg & 15;
  const float descale = 1.f / 32.f;     // undo the *32 on W_out fp8

#pragma unroll
  for (int mt = 0; mt < 4; mt++){
#pragma unroll
    for (int r = 0; r < 4; r++){
      int rl = wm * 64 + mt * 16 + quad * 4 + r;  // C/D: col=lane&15, row=quad*4+reg (m89)
      float l[4];
#pragma unroll
      for (int nt = 0; nt < 4; nt++) l[nt] = fmaf(acc[mt][nt][r], descale, bv[nt]);
      if (bn == 0 && wn == 0 && c16 == 0) blank_g[lin0 + rl] = l[0];
      if (ownL && c16 == tgc){
        float v = l[0];
#pragma unroll
        for (int k = 1; k < 4; k++) v = (ntO == k) ? l[k] : v;
        lbl_g[lin0 + rl] = v;
      }
      float s = __expf(l[0]) + __expf(l[1]) + __expf(l[2]) + __expf(l[3]);
      s += __shfl_xor(s, 1, 64);
      s += __shfl_xor(s, 2, 64);
      s += __shfl_xor(s, 4, 64);
      s += __shfl_xor(s, 8, 64);
      if (c16 == 0) redS[wn][rl] = s;
    }
  }
  __syncthreads();
  if (tid < 128)
    ps[(size_t)bn * cM + lin0 + tid] = redS[0][tid] + redS[1][tid];
}

// ------------- parallel lse merge: 8 ps planes -> blankd/lbld -------------
__global__ __launch_bounds__(256) void k_lse(
    const float* __restrict__ ps, const float* __restrict__ blank_g,
    const float* __restrict__ lbl_g,
    float* __restrict__ blankd, float* __restrict__ lbld)
{
  int cell = blockIdx.x * 256 + threadIdx.x;   // 66560 = 260*256
  float S = 0.f;
#pragma unroll
  for (int p = 0; p < 8; p++) S += ps[(size_t)p * cM + cell];
  float lse = __logf(S);
  int u = (cell % cTU) >> 8;
  blankd[cell] = blank_g[cell] - lse;
  lbld[cell] = (u < cU) ? (lbl_g[cell] - lse) : NEGF;
}

// ------------- RNN-T alpha DP: SKIP-2 diagonal steps -------------
// r14 measured 527 cyc/diag (chain = bpermute + 2 logadds + issue, single wave).
// Two diagonals fused: alpha[t][u] = logadd3(A[u]+C0, A[u-1]+C1, A[u-2]+C2) over
// diagonal d-2, where C0/C1/C2 are pure bb/lb coefficients computed OFF-CHAIN from
// operands prefetched one fused step ahead (named scalars, r9 scratch lesson).
// Chain per fused step = 2 pipelined bpermutes + depth-2 logadd tree (~270 cyc / 2 diag).
// u=64 track is out of the loop: lane 63 logs alpha[t][63] to sS[]; a post-pass 1-D
// recurrence (only when tl==64) finishes it. Label rows >= tl NEGF'd at staging.
__global__ __launch_bounds__(256) void k_dp(
    const float* __restrict__ blankd, const float* __restrict__ lbld,
    const int* __restrict__ in_len, const int* __restrict__ tgt_len,
    float* __restrict__ afin)
{
  __shared__ float sbb[cTU];   // 65 KB, (u,t): index u*256+t
  __shared__ float slb[cTU];   // 65 KB
  __shared__ float sS[256];    // alpha[t][63] history (lane 63)
  int b = blockIdx.x;
  int tl  = tgt_len[b];                // 32..64
  size_t base = (size_t)b * cTU;
  for (int i = threadIdx.x; i < cTU / 4; i += 256){
    ((float4*)sbb)[i] = ((const float4*)(blankd + base))[i];
    float4 v = ((const float4*)(lbld + base))[i];
    int row = (i * 4) >> 8;            // float4 never crosses a 256-elem row
    if (row >= tl){ v.x = NEGF; v.y = NEGF; v.z = NEGF; v.w = NEGF; }
    ((float4*)slb)[i] = v;
  }
  __syncthreads();
  if (threadIdx.x >= 64) return;

  int u = threadIdx.x;                 // 0..63
  int til = in_len[b] - 1;
  bool cap64 = (tl == 64);
  bool isTL = (u == tl);
  const float* pbu  = sbb + (u << 8);
  const float* pbu1 = sbb + (((u >= 1) ? u - 1 : 0) << 8);
  const float* plu1 = slb + (((u >= 1) ? u - 1 : 0) << 8);
  const float* plu2 = slb + (((u >= 2) ? u - 2 : 0) << 8);
  bool u1 = (u >= 1), u2 = (u >= 2);
  float fb = pbu[til];                 // blank at (u, til); used by lane tl only

  float A = (u == 0) ? 0.f : NEGF;     // alpha on even diagonal d = 2g
  float res = 0.f;

  auto ld = [&](const float* p, int i, bool ok) -> float {
    bool v = ok & (i >= 0) & (i <= 255);
    int ic = (i < 0) ? 0 : ((i > 255) ? 255 : i);
    float x = p[ic];
    return v ? x : NEGF;
  };

  // operands for fused step g (target diag D=2g+2, t = i0+2, i0 = 2g-u)
  int i0 = -u;
  float o0 = ld(pbu,  i0,     true);   // bb[t-2][u]
  float o1 = ld(pbu,  i0 + 1, true);   // bb[t-1][u]
  float o2 = ld(plu1, i0 + 1, u1);     // lb[t-1][u-1]
  float o3 = ld(pbu1, i0 + 1, u1);     // bb[t-1][u-1]
  float o4 = ld(plu1, i0 + 2, u1);     // lb[t][u-1]
  float o5 = ld(plu2, i0 + 2, u2);     // lb[t][u-2]

  for (int g = 0; g < 159; g++){
    float c0 = o0, c1 = o1, c2 = o2, c3 = o3, c4 = o4, c5 = o5;
    int i0n = i0 + 2;
    o0 = ld(pbu,  i0n,     true);
    o1 = ld(pbu,  i0n + 1, true);
    o2 = ld(plu1, i0n + 1, u1);
    o3 = ld(pbu1, i0n + 1, u1);
    o4 = ld(plu1, i0n + 2, u1);
    o5 = ld(plu2, i0n + 2, u2);

    float up1 = __shfl_up(A, 1, 64);
    float up2 = __shfl_up(A, 2, 64);

    // coefficients: off the shuffle/logadd chain
    float C0 = c0 + c1;
    float C1 = logadd(c2 + c1, c3 + c4);
    float C2 = c5 + c4;

    // intermediate diagonal d = 2g+1 (cell (i0+1, u))
    bool tv1 = (i0 + 1 >= 0) & (i0 + 1 <= 255);
    float Amid = logadd(A + c0, up1 + c2);
    Amid = tv1 ? Amid : NEGF;
    // final diagonal D = 2g+2 (cell (i0+2, u))
    bool tv2 = (i0 + 2 >= 0) & (i0 + 2 <= 255);
    float Anew = logadd(logadd(A + C0, up1 + C1), up2 + C2);
    Anew = tv2 ? Anew : NEGF;

    if (isTL && (i0 + 1) == til) res = Amid + fb;
    if (isTL && (i0 + 2) == til) res = Anew + fb;
    if (u == 63){
      if (tv1) sS[i0 + 1] = Amid;
      if (tv2) sS[i0 + 2] = Anew;
    }
    A = Anew;
    i0 = i0n;
  }
  // diag 319's only valid cell is u=64 (t=255) -> covered by the post-pass.

  if (cap64){
    const float* pb64 = sbb + (64 << 8);
    const float* pl63 = slb + (63 << 8);
    float A64 = sS[0] + pl63[0];       // alpha[0][64]
    for (int t = 1; t <= til; t++)
      A64 = logadd(A64 + pb64[t - 1], sS[t] + pl63[t]);
    if (u == 0) res = A64 + pb64[til];
  }

  // exactly one lane holds the finish value; butterfly-sum broadcasts it
  res += __shfl_xor(res, 1, 64);
  res += __shfl_xor(res, 2, 64);
  res += __shfl_xor(res, 4, 64);
  res += __shfl_xor(res, 8, 64);
  res += __shfl_xor(res, 16, 64);
  res += __shfl_xor(res, 32, 64);
  if (u == 0) afin[b] = res;
}

__global__ void k_final(const float* __restrict__ afin, float* __restrict__ out){
  if (threadIdx.x == 0)
    out[0] = -0.25f * (afin[0] + afin[1] + afin[2] + afin[3]);
}

extern "C" void kernel_launch(void* const* d_in, const int* in_sizes, int n_in,
                              void* d_out, int out_size, void* d_ws, size_t ws_size,
                              hipStream_t stream)
{
  (void)in_sizes; (void)n_in; (void)out_size; (void)ws_size;
  const float* inputs = (const float*)d_in[0];   // (4,256,80)
  const float* W_enc  = (const float*)d_in[1];   // (80,512)
  const float* emb    = (const float*)d_in[2];   // (1024,512)
  const float* W_jenc = (const float*)d_in[3];   // (512,512)
  const float* W_jdec = (const float*)d_in[4];   // (512,512)
  const float* b_j    = (const float*)d_in[5];   // (512)
  const float* W_out  = (const float*)d_in[6];   // (512,1024)
  const float* b_out  = (const float*)d_in[7];   // (1024)
  const int* targets  = (const int*)d_in[8];     // (4,64)
  const int* in_len   = (const int*)d_in[9];     // (4)
  const int* tgt_len  = (const int*)d_in[10];    // (4)

  char* w = (char*)d_ws;
  auto alloc = [&](size_t bytes){ char* p = w; w += (bytes + 255) & ~(size_t)255; return p; };
  float* Wcomb   = (float*)alloc((size_t)80 * 512 * 4);
  float* e       = (float*)alloc((size_t)1024 * 512 * 4);
  float* dmatb   = (float*)alloc((size_t)260 * 512 * 4);
  float* blank_g = (float*)alloc((size_t)cM * 4);
  float* lbl_g   = (float*)alloc((size_t)cM * 4);
  float* ps      = (float*)alloc((size_t)8 * cM * 4);
  float* blankd  = (float*)alloc((size_t)cM * 4);
  float* lbld    = (float*)alloc((size_t)cM * 4);
  float* afin    = (float*)alloc(256);
  uchar_t* Hbf8  = (uchar_t*)alloc((size_t)520 * 65536);
  uchar_t* WTf8  = (uchar_t*)alloc((size_t)4 * 131072);

  k_pre<<<202, 256, 0, stream>>>(W_enc, W_jenc, Wcomb, emb, targets, W_jdec, b_j, dmatb,
                                 W_out, WTf8);
  k_gemm_e<<<dim3(2, 256), 256, 0, stream>>>(inputs, Wcomb, e);
  k_hf<<<520, 256, 0, stream>>>(e, dmatb, Hbf8);
  k_joint<<<4160, 256, 0, stream>>>(Hbf8, WTf8, b_out, targets, ps, blank_g, lbl_g);
  k_lse<<<260, 256, 0, stream>>>(ps, blank_g, lbl_g, blankd, lbld);
  k_dp<<<4, 256, 0, stream>>>(blankd, lbld, in_len, tgt_len, afin);
  k_final<<<1, 64, 0, stream>>>(afin, (float*)d_out);
}